// Round 4
// baseline (1075.655 us; speedup 1.0000x reference)
//
#include <hip/hip_runtime.h>

// BotRGCN 4-layer forward.
// Round 9: fused RGCN, grid-limited occupancy fix.
//  - Round-8 post-mortem: occupancy capped at 28% by GRID SIZE (782 blocks =
//    3/CU), not LDS. Also 2.3x write amplification from scattered 64B epilogue
//    stores (partial-line RMW: WRITE 59.8 MB vs 25.6 ideal, FETCH +25 MB).
//  - Fix: 32-row blocks -> grid 1563; LDS 16 KB (A planes) aliased with fp32
//    C-staging buffer; epilogue writes full 512B rows coalesced.
//    launch_bounds(256,6) -> ~6 blocks/CU = 24 waves/CU (~75%).

#define N_NODES 50000
#define N_EDGES 800000
#define R_REL   5
#define NSEG    (N_NODES * R_REL)   // 250000
#define SCAN_BS 1024
#define SCAN_NB ((NSEG + SCAN_BS - 1) / SCAN_BS)   // 245

typedef __attribute__((ext_vector_type(8))) short bf16x8;
typedef __attribute__((ext_vector_type(4))) float f32x4;

__device__ __forceinline__ float lrelu(float v) { return v > 0.f ? v : 0.01f * v; }

__device__ __forceinline__ unsigned short f2bf_rne(float f) {
    unsigned u = __float_as_uint(f);
    return (unsigned short)((u + 0x7fff + ((u >> 16) & 1)) >> 16);
}

// split: hi = trunc-bf16(f), lo = rne-bf16(f - hi)
__device__ __forceinline__ void split1(float f, short& h, short& l) {
    unsigned u = __float_as_uint(f);
    unsigned short hh = (unsigned short)(u >> 16);
    h = (short)hh;
    l = (short)f2bf_rne(f - __uint_as_float((unsigned)hh << 16));
}

__device__ __forceinline__ void split8(const float* f, bf16x8& hi, bf16x8& lo) {
#pragma unroll
    for (int i = 0; i < 8; i++) {
        short h, l;
        split1(f[i], h, l);
        hi[i] = h;
        lo[i] = l;
    }
}

// ---------------- CSR build ----------------
__global__ __launch_bounds__(256) void count_kernel(const int* __restrict__ ei,
                                                    const int* __restrict__ et,
                                                    int* __restrict__ cnt) {
    int e = blockIdx.x * 256 + threadIdx.x;
    if (e >= N_EDGES) return;
    atomicAdd(&cnt[ei[N_EDGES + e] * R_REL + et[e]], 1);
}

__global__ __launch_bounds__(SCAN_BS) void scan1(const int* __restrict__ cnt,
                                                 int* __restrict__ rowptr,
                                                 int* __restrict__ blockSums) {
    __shared__ int s[SCAN_BS];
    int t = threadIdx.x;
    int i = blockIdx.x * SCAN_BS + t;
    int v = (i < NSEG) ? cnt[i] : 0;
    s[t] = v;
    __syncthreads();
#pragma unroll
    for (int off = 1; off < SCAN_BS; off <<= 1) {
        int add = (t >= off) ? s[t - off] : 0;
        __syncthreads();
        s[t] += add;
        __syncthreads();
    }
    if (i < NSEG) rowptr[i] = s[t] - v;
    if (t == SCAN_BS - 1) blockSums[blockIdx.x] = s[t];
}

__global__ __launch_bounds__(256) void scan2(int* __restrict__ blockSums) {
    __shared__ int s[256];
    int t = threadIdx.x;
    int v = (t < SCAN_NB) ? blockSums[t] : 0;
    s[t] = v;
    __syncthreads();
#pragma unroll
    for (int off = 1; off < 256; off <<= 1) {
        int add = (t >= off) ? s[t - off] : 0;
        __syncthreads();
        s[t] += add;
        __syncthreads();
    }
    if (t < SCAN_NB) blockSums[t] = s[t] - v;
}

__global__ __launch_bounds__(SCAN_BS) void scan3(int* __restrict__ rowptr,
                                                 const int* __restrict__ blockSums) {
    int i = blockIdx.x * SCAN_BS + threadIdx.x;
    if (i == 0) rowptr[NSEG] = N_EDGES;
    if (i < NSEG) rowptr[i] += blockSums[blockIdx.x];
}

__global__ __launch_bounds__(256) void fill_kernel(const int* __restrict__ ei,
                                                   const int* __restrict__ et,
                                                   const int* __restrict__ rowptr,
                                                   int* __restrict__ cursor,
                                                   int* __restrict__ srcSorted) {
    int e = blockIdx.x * 256 + threadIdx.x;
    if (e >= N_EDGES) return;
    int seg = ei[N_EDGES + e] * R_REL + et[e];
    int pos = atomicAdd(&cursor[seg], 1);
    srcSorted[rowptr[seg] + pos] = ei[e];
}

// ---------------- weight prep: fp32 W[K][NC] (k-major) -> swizzled fragments ----------------
// out layout: [chunk][plane(hi=0,lo=1)][nt][lane(64)][8]  (shorts)
// fragment value for (c, nt, lane l, j): W[k= c*32 + (l>>4)*8 + j][n= nt*16 + (l&15)]
__global__ __launch_bounds__(256) void build_bswz(const float* __restrict__ W,
                                                  int K, int NC, int NTILES,
                                                  short* __restrict__ out) {
    int tid = blockIdx.x * 256 + threadIdx.x;
    int total = (K / 32) * NTILES * 64;
    if (tid >= total) return;
    int l  = tid & 63;
    int nt = (tid >> 6) % NTILES;
    int c  = tid / (64 * NTILES);
    int n = nt * 16 + (l & 15);
    int k0 = c * 32 + (l >> 4) * 8;
    float f[8];
#pragma unroll
    for (int j = 0; j < 8; j++) f[j] = W[(size_t)(k0 + j) * NC + n];
    bf16x8 hi, lo;
    split8(f, hi, lo);
    size_t base = (size_t)c * (2 * NTILES * 512);
    *(bf16x8*)(out + base + ((size_t)nt * 64 + l) * 8) = hi;
    *(bf16x8*)(out + base + (size_t)NTILES * 512 + ((size_t)nt * 64 + l) * 8) = lo;
}

// ---------------- fused RGCN layer ----------------
// Block: 256 threads, 32 output nodes. Phases: rel 0..4 then root.
// Phase: [sync] stage A-tile (aggregate / root copy) ; sync ; GEMM.
// Epilogue staged through LDS for full-line coalesced C writes.
__global__ __launch_bounds__(256, 6) void rgcn_fused(const float* __restrict__ xf,
                                                     const int* __restrict__ rowptr,
                                                     const int* __restrict__ srcSorted,
                                                     const short* __restrict__ bz,
                                                     const float* __restrict__ rgcn_b,
                                                     float* __restrict__ xn, int M) {
    __shared__ __align__(16) char smem[16384];
    short* AhS = (short*)smem;            // [4 chunks][1024]  8 KB
    short* AlS = (short*)(smem + 8192);   // 8 KB
    float* Co  = (float*)smem;            // [32][128] fp32 (aliases A planes)

    const int t = threadIdx.x;
    const int m0 = blockIdx.x * 32;
    const int w = t >> 6, l = t & 63;
    const int q = l >> 4, ln = l & 15;
    const int mw = w >> 1, nw = w & 1;   // wave -> (m-tile, n-half)

    // staging role: row rr, 16-float k-slice q8
    const int rr = t & 31;
    const int q8 = t >> 5;               // 0..7
    const int node = m0 + rr;
    const int cch = q8 >> 1;             // chunk 0..3
    const int kq0 = (q8 & 1) * 2;        // first k-quarter in chunk
    const int sidx = cch * 1024 + (rr >> 4) * 512 + (kq0 * 16 + (rr & 15)) * 8;

    f32x4 acc[4];
#pragma unroll
    for (int nt = 0; nt < 4; nt++) acc[nt] = (f32x4)0.f;

    auto STAGE = [&](const float* ag) {   // 16 scaled floats -> 2 hi/lo fragments
        bf16x8 hv, lv;
        split8(ag, hv, lv);
        *(bf16x8*)&AhS[sidx] = hv;
        *(bf16x8*)&AlS[sidx] = lv;
        split8(ag + 8, hv, lv);
        *(bf16x8*)&AhS[sidx + 128] = hv;
        *(bf16x8*)&AlS[sidx + 128] = lv;
    };

    auto AGG = [&](int rel) {
        float ag[16];
#pragma unroll
        for (int j = 0; j < 16; j++) ag[j] = 0.f;
        int beg = 0, end = 0;
        if (node < M) {
            int s = node * R_REL + rel;
            beg = rowptr[s];
            end = rowptr[s + 1];
        }
        int i = beg;
        for (; i + 1 < end; i += 2) {
            int s0 = srcSorted[i], s1 = srcSorted[i + 1];
            const float4* p0 = (const float4*)(xf + (size_t)s0 * 128 + q8 * 16);
            const float4* p1 = (const float4*)(xf + (size_t)s1 * 128 + q8 * 16);
#pragma unroll
            for (int c4 = 0; c4 < 4; c4++) {
                float4 a = p0[c4], b = p1[c4];
                ag[c4 * 4 + 0] += a.x + b.x; ag[c4 * 4 + 1] += a.y + b.y;
                ag[c4 * 4 + 2] += a.z + b.z; ag[c4 * 4 + 3] += a.w + b.w;
            }
        }
        if (i < end) {
            int s0 = srcSorted[i];
            const float4* p0 = (const float4*)(xf + (size_t)s0 * 128 + q8 * 16);
#pragma unroll
            for (int c4 = 0; c4 < 4; c4++) {
                float4 a = p0[c4];
                ag[c4 * 4 + 0] += a.x; ag[c4 * 4 + 1] += a.y;
                ag[c4 * 4 + 2] += a.z; ag[c4 * 4 + 3] += a.w;
            }
        }
        int cnum = end - beg;
        float inv = cnum > 0 ? 1.f / (float)cnum : 0.f;
#pragma unroll
        for (int j = 0; j < 16; j++) ag[j] *= inv;
        STAGE(ag);
    };

    auto ROOT = [&]() {
        int gr = node < M ? node : M - 1;
        float ag[16];
        const float4* p0 = (const float4*)(xf + (size_t)gr * 128 + q8 * 16);
#pragma unroll
        for (int c4 = 0; c4 < 4; c4++) {
            float4 a = p0[c4];
            ag[c4 * 4 + 0] = a.x; ag[c4 * 4 + 1] = a.y;
            ag[c4 * 4 + 2] = a.z; ag[c4 * 4 + 3] = a.w;
        }
        STAGE(ag);
    };

    // GEMM one relation: 4 chunks, wave's m-tile mw, n-tiles nw*4..nw*4+3.
    auto GEMMP = [&](const short* bzr) {
#pragma unroll
        for (int c = 0; c < 4; c++) {
            bf16x8 ah = *(const bf16x8*)&AhS[c * 1024 + mw * 512 + l * 8];
            bf16x8 al = *(const bf16x8*)&AlS[c * 1024 + mw * 512 + l * 8];
#pragma unroll
            for (int nt = 0; nt < 4; nt++) {
                int ng = nw * 4 + nt;
                const short* bp = bzr + c * 8192 + ng * 512 + l * 8;
                bf16x8 bh = *(const bf16x8*)(bp);
                bf16x8 bl2 = *(const bf16x8*)(bp + 4096);
                acc[nt] = __builtin_amdgcn_mfma_f32_16x16x32_bf16(ah, bh, acc[nt], 0, 0, 0);
                acc[nt] = __builtin_amdgcn_mfma_f32_16x16x32_bf16(ah, bl2, acc[nt], 0, 0, 0);
                acc[nt] = __builtin_amdgcn_mfma_f32_16x16x32_bf16(al, bh, acc[nt], 0, 0, 0);
            }
        }
    };

#pragma unroll 1
    for (int r = 0; r < 6; r++) {
        if (r > 0) __syncthreads();       // prior GEMM's LDS reads complete
        if (r < 5) AGG(r); else ROOT();
        __syncthreads();                  // A-tile staged
        GEMMP(bz + (size_t)r * 32768);
    }

    // epilogue: stage C in LDS, then full-row coalesced global writes
    __syncthreads();                      // last GEMM's LDS reads complete
#pragma unroll
    for (int nt = 0; nt < 4; nt++) {
        int col = (nw * 4 + nt) * 16 + ln;
        float bv = rgcn_b[col];
        f32x4 v = acc[nt];
#pragma unroll
        for (int i = 0; i < 4; i++) {
            int row = mw * 16 + q * 4 + i;
            Co[row * 128 + col] = v[i] + bv;
        }
    }
    __syncthreads();
#pragma unroll
    for (int it = 0; it < 4; it++) {
        int idx = it * 256 + t;           // 0..1023 float4 slots
        int row = idx >> 5, c4 = idx & 31;
        int m = m0 + row;
        if (m < M)
            ((float4*)(xn + (size_t)m * 128))[c4] = ((const float4*)(Co + row * 128))[c4];
    }
}

// ---------------- MFMA bf16x3 GEMM, fp32 A, fp32 C (encoders / input / head) ----------------
template <int NT, bool ACT>
__global__ __launch_bounds__(256) void mfma_gemm(const float* __restrict__ A, int K,
                                                 const short* __restrict__ Bswz,
                                                 const float* __restrict__ bias,
                                                 float* __restrict__ C, int M,
                                                 int colofs) {
    constexpr int NH = NT / 2;
    __shared__ short Ahi[2048], Alo[2048];
    __shared__ short Bs[NT * 1024];
    const int t = threadIdx.x;
    const int m0 = blockIdx.x * 64;
    const int w = t >> 6, l = t & 63;
    const int q = l >> 4, ln = l & 15;
    const int mw = w >> 1, nw = w & 1;

    f32x4 acc[2][NH];
#pragma unroll
    for (int mt = 0; mt < 2; mt++)
#pragma unroll
        for (int nt = 0; nt < NH; nt++) acc[mt][nt] = (f32x4)0.f;

    const int nchunks = K / 32;
    const int r = t >> 2, qq = t & 3;
    const int aidx = (r >> 4) * 512 + qq * 128 + (r & 15) * 8;
    int gr = m0 + r; if (gr >= M) gr = M - 1;

    for (int c = 0; c < nchunks; c++) {
        __syncthreads();
        {
            const float* ap = A + (size_t)gr * K + c * 32 + qq * 8;
            float f[8];
            *(float4*)&f[0] = ((const float4*)ap)[0];
            *(float4*)&f[4] = ((const float4*)ap)[1];
            bf16x8 h0, l0;
            split8(f, h0, l0);
            *(bf16x8*)&Ahi[aidx] = h0;
            *(bf16x8*)&Alo[aidx] = l0;
        }
        {
            const short* gb = Bswz + (size_t)c * (NT * 1024);
#pragma unroll
            for (int i = 0; i < NH; i++) {
                int idx = i * 256 + t;
                *(bf16x8*)&Bs[idx * 8] = *(const bf16x8*)(gb + (size_t)idx * 8);
            }
        }
        __syncthreads();

        bf16x8 a_hi[2], a_lo[2];
#pragma unroll
        for (int mt = 0; mt < 2; mt++) {
            a_hi[mt] = *(const bf16x8*)&Ahi[(mw * 2 + mt) * 512 + l * 8];
            a_lo[mt] = *(const bf16x8*)&Alo[(mw * 2 + mt) * 512 + l * 8];
        }
#pragma unroll
        for (int nt = 0; nt < NH; nt++) {
            int ng = nw * NH + nt;
            bf16x8 bh = *(const bf16x8*)&Bs[(ng * 64 + l) * 8];
            bf16x8 bl = *(const bf16x8*)&Bs[NT * 512 + (ng * 64 + l) * 8];
#pragma unroll
            for (int mt = 0; mt < 2; mt++) {
                acc[mt][nt] = __builtin_amdgcn_mfma_f32_16x16x32_bf16(a_hi[mt], bh, acc[mt][nt], 0, 0, 0);
                acc[mt][nt] = __builtin_amdgcn_mfma_f32_16x16x32_bf16(a_hi[mt], bl, acc[mt][nt], 0, 0, 0);
                acc[mt][nt] = __builtin_amdgcn_mfma_f32_16x16x32_bf16(a_lo[mt], bh, acc[mt][nt], 0, 0, 0);
            }
        }
    }

#pragma unroll
    for (int nt = 0; nt < NH; nt++) {
        int ng = nw * NH + nt;
        int col = colofs + ng * 16 + ln;
        float bv = bias[ng * 16 + ln];
#pragma unroll
        for (int mt = 0; mt < 2; mt++) {
            f32x4 v = acc[mt][nt];
#pragma unroll
            for (int i = 0; i < 4; i++) {
                int m = m0 + (mw * 2 + mt) * 16 + q * 4 + i;
                if (m < M) {
                    float xv = v[i] + bv;
                    if (ACT) xv = lrelu(xv);
                    C[(size_t)m * 128 + col] = xv;
                }
            }
        }
    }
}

// ---------------- small feature encoders (K=6, K=11) ----------------
__global__ __launch_bounds__(256) void encode_small(const float* __restrict__ num_prop,
                                                    const float* __restrict__ cat_prop,
                                                    const float* __restrict__ W_np,
                                                    const float* __restrict__ b_np,
                                                    const float* __restrict__ W_cp,
                                                    const float* __restrict__ b_cp,
                                                    float* __restrict__ x) {
    int t = blockIdx.x * 256 + threadIdx.x;
    int node = t >> 6;
    int jj = t & 63;
    if (node >= N_NODES) return;
    if (jj < 32) {
        float acc = b_np[jj];
        const float* row = num_prop + (size_t)node * 6;
#pragma unroll
        for (int k = 0; k < 6; k++) acc = fmaf(row[k], W_np[k * 32 + jj], acc);
        x[(size_t)node * 128 + 64 + jj] = lrelu(acc);
    } else {
        int j = jj - 32;
        float acc = b_cp[j];
        const float* row = cat_prop + (size_t)node * 11;
#pragma unroll
        for (int k = 0; k < 11; k++) acc = fmaf(row[k], W_cp[k * 32 + j], acc);
        x[(size_t)node * 128 + 96 + j] = lrelu(acc);
    }
}

// ---------------- final projection 128 -> 2 ----------------
__global__ __launch_bounds__(256) void out_proj(const float* __restrict__ X,
                                                const float* __restrict__ W,
                                                const float* __restrict__ b,
                                                float* __restrict__ out, int M) {
    int n = blockIdx.x * 256 + threadIdx.x;
    if (n >= M) return;
    float a0 = b[0], a1 = b[1];
    const float4* xr = (const float4*)(X + (size_t)n * 128);
#pragma unroll
    for (int k4 = 0; k4 < 32; k4++) {
        float4 v = xr[k4];
        a0 = fmaf(v.x, W[(k4 * 4 + 0) * 2 + 0], a0);
        a1 = fmaf(v.x, W[(k4 * 4 + 0) * 2 + 1], a1);
        a0 = fmaf(v.y, W[(k4 * 4 + 1) * 2 + 0], a0);
        a1 = fmaf(v.y, W[(k4 * 4 + 1) * 2 + 1], a1);
        a0 = fmaf(v.z, W[(k4 * 4 + 2) * 2 + 0], a0);
        a1 = fmaf(v.z, W[(k4 * 4 + 2) * 2 + 1], a1);
        a0 = fmaf(v.w, W[(k4 * 4 + 3) * 2 + 0], a0);
        a1 = fmaf(v.w, W[(k4 * 4 + 3) * 2 + 1], a1);
    }
    out[(size_t)n * 2 + 0] = a0;
    out[(size_t)n * 2 + 1] = a1;
}

static inline size_t align64(size_t x) { return (x + 63) & ~(size_t)63; }

extern "C" void kernel_launch(void* const* d_in, const int* in_sizes, int n_in,
                              void* d_out, int out_size, void* d_ws, size_t ws_size,
                              hipStream_t stream) {
    const float* des      = (const float*)d_in[0];
    const float* tweet    = (const float*)d_in[1];
    const float* num_prop = (const float*)d_in[2];
    const float* cat_prop = (const float*)d_in[3];
    const int*   edge_index = (const int*)d_in[4];
    const int*   edge_type  = (const int*)d_in[5];
    const float* W_des = (const float*)d_in[6];  const float* b_des = (const float*)d_in[7];
    const float* W_tw  = (const float*)d_in[8];  const float* b_tw  = (const float*)d_in[9];
    const float* W_np  = (const float*)d_in[10]; const float* b_np  = (const float*)d_in[11];
    const float* W_cp  = (const float*)d_in[12]; const float* b_cp  = (const float*)d_in[13];
    const float* W_in  = (const float*)d_in[14]; const float* b_in  = (const float*)d_in[15];
    const float* rel_w = (const float*)d_in[16]; const float* root_w = (const float*)d_in[17];
    const float* rgcn_b = (const float*)d_in[18];
    const float* W_o1  = (const float*)d_in[19]; const float* b_o1  = (const float*)d_in[20];
    const float* W_o2  = (const float*)d_in[21]; const float* b_o2  = (const float*)d_in[22];
    float* out = (float*)d_out;

    // workspace layout
    char* p = (char*)d_ws;
    float* xA  = (float*)p;            p += (size_t)N_NODES * 128 * 4;
    float* xB  = (float*)p;            p += (size_t)N_NODES * 128 * 4;
    int* cnt       = (int*)p;          p += (size_t)NSEG * 4;
    int* rowptr    = (int*)p;          p += (size_t)(NSEG + 1) * 4;
    int* cursor    = (int*)p;          p += (size_t)NSEG * 4;
    int* srcSorted = (int*)p;          p += (size_t)N_EDGES * 4;
    int* blockSums = (int*)p;          p += (size_t)256 * 4;
    p = (char*)align64((size_t)p);
    // swizzled weights (shorts)
    short* bz_cat = (short*)p;         p += (size_t)6 * 32768 * 2;   // 5 rel + root
    short* bz_in  = (short*)p;         p += (size_t)32768 * 2;
    short* bz_o1  = (short*)p;         p += (size_t)32768 * 2;
    short* bz_des = (short*)p;         p += (size_t)24 * 2048 * 2;
    short* bz_tw  = (short*)p;         p += (size_t)24 * 2048 * 2;

    // 0. weight prep
    for (int r = 0; r < R_REL; r++)
        build_bswz<<<8, 256, 0, stream>>>(rel_w + (size_t)r * 128 * 128, 128, 128, 8,
                                          bz_cat + (size_t)r * 32768);
    build_bswz<<<8, 256, 0, stream>>>(root_w, 128, 128, 8, bz_cat + (size_t)5 * 32768);
    build_bswz<<<8, 256, 0, stream>>>(W_in, 128, 128, 8, bz_in);
    build_bswz<<<8, 256, 0, stream>>>(W_o1, 128, 128, 8, bz_o1);
    build_bswz<<<12, 256, 0, stream>>>(W_des, 768, 32, 2, bz_des);
    build_bswz<<<12, 256, 0, stream>>>(W_tw, 768, 32, 2, bz_tw);

    // 1. CSR build (layer-invariant)
    hipMemsetAsync(cnt, 0, (size_t)NSEG * sizeof(int), stream);
    hipMemsetAsync(cursor, 0, (size_t)NSEG * sizeof(int), stream);
    count_kernel<<<(N_EDGES + 255) / 256, 256, 0, stream>>>(edge_index, edge_type, cnt);
    scan1<<<SCAN_NB, SCAN_BS, 0, stream>>>(cnt, rowptr, blockSums);
    scan2<<<1, 256, 0, stream>>>(blockSums);
    scan3<<<SCAN_NB, SCAN_BS, 0, stream>>>(rowptr, blockSums);
    fill_kernel<<<(N_EDGES + 255) / 256, 256, 0, stream>>>(
        edge_index, edge_type, rowptr, cursor, srcSorted);

    const int gm = (N_NODES + 63) / 64;    // 782 (dense GEMMs, 64-row tiles)
    const int gm32 = (N_NODES + 31) / 32;  // 1563 (fused RGCN, 32-row tiles)

    // 2. encode -> xA fp32
    encode_small<<<(N_NODES * 64 + 255) / 256, 256, 0, stream>>>(
        num_prop, cat_prop, W_np, b_np, W_cp, b_cp, xA);
    mfma_gemm<2, true><<<gm, 256, 0, stream>>>(des, 768, bz_des, b_des, xA, N_NODES, 0);
    mfma_gemm<2, true><<<gm, 256, 0, stream>>>(tweet, 768, bz_tw, b_tw, xA, N_NODES, 32);

    // 3. input linear: xA -> xB
    mfma_gemm<8, true><<<gm, 256, 0, stream>>>(xA, 128, bz_in, b_in, xB, N_NODES, 0);

    // 4. RGCN x4 (fused gather-aggregate-GEMM)
    float* cur = xB; float* nxt = xA;
    for (int lyr = 0; lyr < 4; lyr++) {
        rgcn_fused<<<gm32, 256, 0, stream>>>(cur, rowptr, srcSorted, bz_cat, rgcn_b, nxt, N_NODES);
        float* tmp = cur; cur = nxt; nxt = tmp;
    }

    // 5. output head
    mfma_gemm<8, true><<<gm, 256, 0, stream>>>(cur, 128, bz_o1, b_o1, nxt, N_NODES, 0);
    out_proj<<<(N_NODES + 255) / 256, 256, 0, stream>>>(nxt, W_o2, b_o2, out, N_NODES);
}

// Round 5
// 1025.082 us; speedup vs baseline: 1.0493x; 1.0493x over previous
//
#include <hip/hip_runtime.h>

// BotRGCN 4-layer forward.
// Round 10: coalesced gather (fabric-traffic fix).
//  - Rounds 7/8/9: occupancy 17->28->48%, time FLAT (~143us/layer). Bottleneck is
//    L2<-L3 fabric line traffic: old rr=t&31/q8=t>>5 mapping scattered each 512B
//    row-read across 4 waves as 32x16B requests -> 32 full 128B line fetches per
//    edge (~3.3 GB/layer through fabric, invisible to FETCH_SIZE since x is
//    L3-resident).
//  - Fix: rr=t>>3, q8=t&7 -> 8 consecutive lanes cover one row; each thread reads
//    contiguous 64B; line fetches per edge drop 32 -> 4 (8x fabric reduction).
//    sidx formula unchanged (symbolic in rr/q8). LDS write conflicts rise to
//    ~8-way on staging (accepted: <5% of phase).

#define N_NODES 50000
#define N_EDGES 800000
#define R_REL   5
#define NSEG    (N_NODES * R_REL)   // 250000
#define SCAN_BS 1024
#define SCAN_NB ((NSEG + SCAN_BS - 1) / SCAN_BS)   // 245

typedef __attribute__((ext_vector_type(8))) short bf16x8;
typedef __attribute__((ext_vector_type(4))) float f32x4;

__device__ __forceinline__ float lrelu(float v) { return v > 0.f ? v : 0.01f * v; }

__device__ __forceinline__ unsigned short f2bf_rne(float f) {
    unsigned u = __float_as_uint(f);
    return (unsigned short)((u + 0x7fff + ((u >> 16) & 1)) >> 16);
}

// split: hi = trunc-bf16(f), lo = rne-bf16(f - hi)
__device__ __forceinline__ void split1(float f, short& h, short& l) {
    unsigned u = __float_as_uint(f);
    unsigned short hh = (unsigned short)(u >> 16);
    h = (short)hh;
    l = (short)f2bf_rne(f - __uint_as_float((unsigned)hh << 16));
}

__device__ __forceinline__ void split8(const float* f, bf16x8& hi, bf16x8& lo) {
#pragma unroll
    for (int i = 0; i < 8; i++) {
        short h, l;
        split1(f[i], h, l);
        hi[i] = h;
        lo[i] = l;
    }
}

// ---------------- CSR build ----------------
__global__ __launch_bounds__(256) void count_kernel(const int* __restrict__ ei,
                                                    const int* __restrict__ et,
                                                    int* __restrict__ cnt) {
    int e = blockIdx.x * 256 + threadIdx.x;
    if (e >= N_EDGES) return;
    atomicAdd(&cnt[ei[N_EDGES + e] * R_REL + et[e]], 1);
}

__global__ __launch_bounds__(SCAN_BS) void scan1(const int* __restrict__ cnt,
                                                 int* __restrict__ rowptr,
                                                 int* __restrict__ blockSums) {
    __shared__ int s[SCAN_BS];
    int t = threadIdx.x;
    int i = blockIdx.x * SCAN_BS + t;
    int v = (i < NSEG) ? cnt[i] : 0;
    s[t] = v;
    __syncthreads();
#pragma unroll
    for (int off = 1; off < SCAN_BS; off <<= 1) {
        int add = (t >= off) ? s[t - off] : 0;
        __syncthreads();
        s[t] += add;
        __syncthreads();
    }
    if (i < NSEG) rowptr[i] = s[t] - v;
    if (t == SCAN_BS - 1) blockSums[blockIdx.x] = s[t];
}

__global__ __launch_bounds__(256) void scan2(int* __restrict__ blockSums) {
    __shared__ int s[256];
    int t = threadIdx.x;
    int v = (t < SCAN_NB) ? blockSums[t] : 0;
    s[t] = v;
    __syncthreads();
#pragma unroll
    for (int off = 1; off < 256; off <<= 1) {
        int add = (t >= off) ? s[t - off] : 0;
        __syncthreads();
        s[t] += add;
        __syncthreads();
    }
    if (t < SCAN_NB) blockSums[t] = s[t] - v;
}

__global__ __launch_bounds__(SCAN_BS) void scan3(int* __restrict__ rowptr,
                                                 const int* __restrict__ blockSums) {
    int i = blockIdx.x * SCAN_BS + threadIdx.x;
    if (i == 0) rowptr[NSEG] = N_EDGES;
    if (i < NSEG) rowptr[i] += blockSums[blockIdx.x];
}

__global__ __launch_bounds__(256) void fill_kernel(const int* __restrict__ ei,
                                                   const int* __restrict__ et,
                                                   const int* __restrict__ rowptr,
                                                   int* __restrict__ cursor,
                                                   int* __restrict__ srcSorted) {
    int e = blockIdx.x * 256 + threadIdx.x;
    if (e >= N_EDGES) return;
    int seg = ei[N_EDGES + e] * R_REL + et[e];
    int pos = atomicAdd(&cursor[seg], 1);
    srcSorted[rowptr[seg] + pos] = ei[e];
}

// ---------------- weight prep: fp32 W[K][NC] (k-major) -> swizzled fragments ----------------
// out layout: [chunk][plane(hi=0,lo=1)][nt][lane(64)][8]  (shorts)
// fragment value for (c, nt, lane l, j): W[k= c*32 + (l>>4)*8 + j][n= nt*16 + (l&15)]
__global__ __launch_bounds__(256) void build_bswz(const float* __restrict__ W,
                                                  int K, int NC, int NTILES,
                                                  short* __restrict__ out) {
    int tid = blockIdx.x * 256 + threadIdx.x;
    int total = (K / 32) * NTILES * 64;
    if (tid >= total) return;
    int l  = tid & 63;
    int nt = (tid >> 6) % NTILES;
    int c  = tid / (64 * NTILES);
    int n = nt * 16 + (l & 15);
    int k0 = c * 32 + (l >> 4) * 8;
    float f[8];
#pragma unroll
    for (int j = 0; j < 8; j++) f[j] = W[(size_t)(k0 + j) * NC + n];
    bf16x8 hi, lo;
    split8(f, hi, lo);
    size_t base = (size_t)c * (2 * NTILES * 512);
    *(bf16x8*)(out + base + ((size_t)nt * 64 + l) * 8) = hi;
    *(bf16x8*)(out + base + (size_t)NTILES * 512 + ((size_t)nt * 64 + l) * 8) = lo;
}

// ---------------- fused RGCN layer ----------------
// Block: 256 threads, 32 output nodes. Phases: rel 0..4 then root.
// Phase: [sync] stage A-tile (aggregate / root copy) ; sync ; GEMM.
// Gather: 8 consecutive lanes per node row; each thread reads contiguous 64B.
__global__ __launch_bounds__(256, 6) void rgcn_fused(const float* __restrict__ xf,
                                                     const int* __restrict__ rowptr,
                                                     const int* __restrict__ srcSorted,
                                                     const short* __restrict__ bz,
                                                     const float* __restrict__ rgcn_b,
                                                     float* __restrict__ xn, int M) {
    __shared__ __align__(16) char smem[16384];
    short* AhS = (short*)smem;            // [4 chunks][1024]  8 KB
    short* AlS = (short*)(smem + 8192);   // 8 KB
    float* Co  = (float*)smem;            // [32][128] fp32 (aliases A planes)

    const int t = threadIdx.x;
    const int m0 = blockIdx.x * 32;
    const int w = t >> 6, l = t & 63;
    const int q = l >> 4, ln = l & 15;
    const int mw = w >> 1, nw = w & 1;   // wave -> (m-tile, n-half)

    // staging role: 8 consecutive lanes cover one row (coalesced gather)
    const int rr = t >> 3;               // row 0..31
    const int q8 = t & 7;                // 16-float k-slice 0..7
    const int node = m0 + rr;
    const int cch = q8 >> 1;             // chunk 0..3
    const int kq0 = (q8 & 1) * 2;        // first k-quarter in chunk
    const int sidx = cch * 1024 + (rr >> 4) * 512 + (kq0 * 16 + (rr & 15)) * 8;

    f32x4 acc[4];
#pragma unroll
    for (int nt = 0; nt < 4; nt++) acc[nt] = (f32x4)0.f;

    auto STAGE = [&](const float* ag) {   // 16 scaled floats -> 2 hi/lo fragments
        bf16x8 hv, lv;
        split8(ag, hv, lv);
        *(bf16x8*)&AhS[sidx] = hv;
        *(bf16x8*)&AlS[sidx] = lv;
        split8(ag + 8, hv, lv);
        *(bf16x8*)&AhS[sidx + 128] = hv;
        *(bf16x8*)&AlS[sidx + 128] = lv;
    };

    auto AGG = [&](int rel) {
        float ag[16];
#pragma unroll
        for (int j = 0; j < 16; j++) ag[j] = 0.f;
        int beg = 0, end = 0;
        if (node < M) {
            int s = node * R_REL + rel;
            beg = rowptr[s];
            end = rowptr[s + 1];
        }
        int i = beg;
        for (; i + 1 < end; i += 2) {
            int s0 = srcSorted[i], s1 = srcSorted[i + 1];
            const float4* p0 = (const float4*)(xf + (size_t)s0 * 128 + q8 * 16);
            const float4* p1 = (const float4*)(xf + (size_t)s1 * 128 + q8 * 16);
#pragma unroll
            for (int c4 = 0; c4 < 4; c4++) {
                float4 a = p0[c4], b = p1[c4];
                ag[c4 * 4 + 0] += a.x + b.x; ag[c4 * 4 + 1] += a.y + b.y;
                ag[c4 * 4 + 2] += a.z + b.z; ag[c4 * 4 + 3] += a.w + b.w;
            }
        }
        if (i < end) {
            int s0 = srcSorted[i];
            const float4* p0 = (const float4*)(xf + (size_t)s0 * 128 + q8 * 16);
#pragma unroll
            for (int c4 = 0; c4 < 4; c4++) {
                float4 a = p0[c4];
                ag[c4 * 4 + 0] += a.x; ag[c4 * 4 + 1] += a.y;
                ag[c4 * 4 + 2] += a.z; ag[c4 * 4 + 3] += a.w;
            }
        }
        int cnum = end - beg;
        float inv = cnum > 0 ? 1.f / (float)cnum : 0.f;
#pragma unroll
        for (int j = 0; j < 16; j++) ag[j] *= inv;
        STAGE(ag);
    };

    auto ROOT = [&]() {
        int gr = node < M ? node : M - 1;
        float ag[16];
        const float4* p0 = (const float4*)(xf + (size_t)gr * 128 + q8 * 16);
#pragma unroll
        for (int c4 = 0; c4 < 4; c4++) {
            float4 a = p0[c4];
            ag[c4 * 4 + 0] = a.x; ag[c4 * 4 + 1] = a.y;
            ag[c4 * 4 + 2] = a.z; ag[c4 * 4 + 3] = a.w;
        }
        STAGE(ag);
    };

    // GEMM one relation: 4 chunks, wave's m-tile mw, n-tiles nw*4..nw*4+3.
    auto GEMMP = [&](const short* bzr) {
#pragma unroll
        for (int c = 0; c < 4; c++) {
            bf16x8 ah = *(const bf16x8*)&AhS[c * 1024 + mw * 512 + l * 8];
            bf16x8 al = *(const bf16x8*)&AlS[c * 1024 + mw * 512 + l * 8];
#pragma unroll
            for (int nt = 0; nt < 4; nt++) {
                int ng = nw * 4 + nt;
                const short* bp = bzr + c * 8192 + ng * 512 + l * 8;
                bf16x8 bh = *(const bf16x8*)(bp);
                bf16x8 bl2 = *(const bf16x8*)(bp + 4096);
                acc[nt] = __builtin_amdgcn_mfma_f32_16x16x32_bf16(ah, bh, acc[nt], 0, 0, 0);
                acc[nt] = __builtin_amdgcn_mfma_f32_16x16x32_bf16(ah, bl2, acc[nt], 0, 0, 0);
                acc[nt] = __builtin_amdgcn_mfma_f32_16x16x32_bf16(al, bh, acc[nt], 0, 0, 0);
            }
        }
    };

#pragma unroll 1
    for (int r = 0; r < 6; r++) {
        if (r > 0) __syncthreads();       // prior GEMM's LDS reads complete
        if (r < 5) AGG(r); else ROOT();
        __syncthreads();                  // A-tile staged
        GEMMP(bz + (size_t)r * 32768);
    }

    // epilogue: stage C in LDS, then full-row coalesced global writes
    __syncthreads();                      // last GEMM's LDS reads complete
#pragma unroll
    for (int nt = 0; nt < 4; nt++) {
        int col = (nw * 4 + nt) * 16 + ln;
        float bv = rgcn_b[col];
        f32x4 v = acc[nt];
#pragma unroll
        for (int i = 0; i < 4; i++) {
            int row = mw * 16 + q * 4 + i;
            Co[row * 128 + col] = v[i] + bv;
        }
    }
    __syncthreads();
#pragma unroll
    for (int it = 0; it < 4; it++) {
        int idx = it * 256 + t;           // 0..1023 float4 slots
        int row = idx >> 5, c4 = idx & 31;
        int m = m0 + row;
        if (m < M)
            ((float4*)(xn + (size_t)m * 128))[c4] = ((const float4*)(Co + row * 128))[c4];
    }
}

// ---------------- MFMA bf16x3 GEMM, fp32 A, fp32 C (encoders / input / head) ----------------
template <int NT, bool ACT>
__global__ __launch_bounds__(256) void mfma_gemm(const float* __restrict__ A, int K,
                                                 const short* __restrict__ Bswz,
                                                 const float* __restrict__ bias,
                                                 float* __restrict__ C, int M,
                                                 int colofs) {
    constexpr int NH = NT / 2;
    __shared__ short Ahi[2048], Alo[2048];
    __shared__ short Bs[NT * 1024];
    const int t = threadIdx.x;
    const int m0 = blockIdx.x * 64;
    const int w = t >> 6, l = t & 63;
    const int q = l >> 4, ln = l & 15;
    const int mw = w >> 1, nw = w & 1;

    f32x4 acc[2][NH];
#pragma unroll
    for (int mt = 0; mt < 2; mt++)
#pragma unroll
        for (int nt = 0; nt < NH; nt++) acc[mt][nt] = (f32x4)0.f;

    const int nchunks = K / 32;
    const int r = t >> 2, qq = t & 3;
    const int aidx = (r >> 4) * 512 + qq * 128 + (r & 15) * 8;
    int gr = m0 + r; if (gr >= M) gr = M - 1;

    for (int c = 0; c < nchunks; c++) {
        __syncthreads();
        {
            const float* ap = A + (size_t)gr * K + c * 32 + qq * 8;
            float f[8];
            *(float4*)&f[0] = ((const float4*)ap)[0];
            *(float4*)&f[4] = ((const float4*)ap)[1];
            bf16x8 h0, l0;
            split8(f, h0, l0);
            *(bf16x8*)&Ahi[aidx] = h0;
            *(bf16x8*)&Alo[aidx] = l0;
        }
        {
            const short* gb = Bswz + (size_t)c * (NT * 1024);
#pragma unroll
            for (int i = 0; i < NH; i++) {
                int idx = i * 256 + t;
                *(bf16x8*)&Bs[idx * 8] = *(const bf16x8*)(gb + (size_t)idx * 8);
            }
        }
        __syncthreads();

        bf16x8 a_hi[2], a_lo[2];
#pragma unroll
        for (int mt = 0; mt < 2; mt++) {
            a_hi[mt] = *(const bf16x8*)&Ahi[(mw * 2 + mt) * 512 + l * 8];
            a_lo[mt] = *(const bf16x8*)&Alo[(mw * 2 + mt) * 512 + l * 8];
        }
#pragma unroll
        for (int nt = 0; nt < NH; nt++) {
            int ng = nw * NH + nt;
            bf16x8 bh = *(const bf16x8*)&Bs[(ng * 64 + l) * 8];
            bf16x8 bl = *(const bf16x8*)&Bs[NT * 512 + (ng * 64 + l) * 8];
#pragma unroll
            for (int mt = 0; mt < 2; mt++) {
                acc[mt][nt] = __builtin_amdgcn_mfma_f32_16x16x32_bf16(a_hi[mt], bh, acc[mt][nt], 0, 0, 0);
                acc[mt][nt] = __builtin_amdgcn_mfma_f32_16x16x32_bf16(a_hi[mt], bl, acc[mt][nt], 0, 0, 0);
                acc[mt][nt] = __builtin_amdgcn_mfma_f32_16x16x32_bf16(a_lo[mt], bh, acc[mt][nt], 0, 0, 0);
            }
        }
    }

#pragma unroll
    for (int nt = 0; nt < NH; nt++) {
        int ng = nw * NH + nt;
        int col = colofs + ng * 16 + ln;
        float bv = bias[ng * 16 + ln];
#pragma unroll
        for (int mt = 0; mt < 2; mt++) {
            f32x4 v = acc[mt][nt];
#pragma unroll
            for (int i = 0; i < 4; i++) {
                int m = m0 + (mw * 2 + mt) * 16 + q * 4 + i;
                if (m < M) {
                    float xv = v[i] + bv;
                    if (ACT) xv = lrelu(xv);
                    C[(size_t)m * 128 + col] = xv;
                }
            }
        }
    }
}

// ---------------- small feature encoders (K=6, K=11) ----------------
__global__ __launch_bounds__(256) void encode_small(const float* __restrict__ num_prop,
                                                    const float* __restrict__ cat_prop,
                                                    const float* __restrict__ W_np,
                                                    const float* __restrict__ b_np,
                                                    const float* __restrict__ W_cp,
                                                    const float* __restrict__ b_cp,
                                                    float* __restrict__ x) {
    int t = blockIdx.x * 256 + threadIdx.x;
    int node = t >> 6;
    int jj = t & 63;
    if (node >= N_NODES) return;
    if (jj < 32) {
        float acc = b_np[jj];
        const float* row = num_prop + (size_t)node * 6;
#pragma unroll
        for (int k = 0; k < 6; k++) acc = fmaf(row[k], W_np[k * 32 + jj], acc);
        x[(size_t)node * 128 + 64 + jj] = lrelu(acc);
    } else {
        int j = jj - 32;
        float acc = b_cp[j];
        const float* row = cat_prop + (size_t)node * 11;
#pragma unroll
        for (int k = 0; k < 11; k++) acc = fmaf(row[k], W_cp[k * 32 + j], acc);
        x[(size_t)node * 128 + 96 + j] = lrelu(acc);
    }
}

// ---------------- final projection 128 -> 2 ----------------
__global__ __launch_bounds__(256) void out_proj(const float* __restrict__ X,
                                                const float* __restrict__ W,
                                                const float* __restrict__ b,
                                                float* __restrict__ out, int M) {
    int n = blockIdx.x * 256 + threadIdx.x;
    if (n >= M) return;
    float a0 = b[0], a1 = b[1];
    const float4* xr = (const float4*)(X + (size_t)n * 128);
#pragma unroll
    for (int k4 = 0; k4 < 32; k4++) {
        float4 v = xr[k4];
        a0 = fmaf(v.x, W[(k4 * 4 + 0) * 2 + 0], a0);
        a1 = fmaf(v.x, W[(k4 * 4 + 0) * 2 + 1], a1);
        a0 = fmaf(v.y, W[(k4 * 4 + 1) * 2 + 0], a0);
        a1 = fmaf(v.y, W[(k4 * 4 + 1) * 2 + 1], a1);
        a0 = fmaf(v.z, W[(k4 * 4 + 2) * 2 + 0], a0);
        a1 = fmaf(v.z, W[(k4 * 4 + 2) * 2 + 1], a1);
        a0 = fmaf(v.w, W[(k4 * 4 + 3) * 2 + 0], a0);
        a1 = fmaf(v.w, W[(k4 * 4 + 3) * 2 + 1], a1);
    }
    out[(size_t)n * 2 + 0] = a0;
    out[(size_t)n * 2 + 1] = a1;
}

static inline size_t align64(size_t x) { return (x + 63) & ~(size_t)63; }

extern "C" void kernel_launch(void* const* d_in, const int* in_sizes, int n_in,
                              void* d_out, int out_size, void* d_ws, size_t ws_size,
                              hipStream_t stream) {
    const float* des      = (const float*)d_in[0];
    const float* tweet    = (const float*)d_in[1];
    const float* num_prop = (const float*)d_in[2];
    const float* cat_prop = (const float*)d_in[3];
    const int*   edge_index = (const int*)d_in[4];
    const int*   edge_type  = (const int*)d_in[5];
    const float* W_des = (const float*)d_in[6];  const float* b_des = (const float*)d_in[7];
    const float* W_tw  = (const float*)d_in[8];  const float* b_tw  = (const float*)d_in[9];
    const float* W_np  = (const float*)d_in[10]; const float* b_np  = (const float*)d_in[11];
    const float* W_cp  = (const float*)d_in[12]; const float* b_cp  = (const float*)d_in[13];
    const float* W_in  = (const float*)d_in[14]; const float* b_in  = (const float*)d_in[15];
    const float* rel_w = (const float*)d_in[16]; const float* root_w = (const float*)d_in[17];
    const float* rgcn_b = (const float*)d_in[18];
    const float* W_o1  = (const float*)d_in[19]; const float* b_o1  = (const float*)d_in[20];
    const float* W_o2  = (const float*)d_in[21]; const float* b_o2  = (const float*)d_in[22];
    float* out = (float*)d_out;

    // workspace layout
    char* p = (char*)d_ws;
    float* xA  = (float*)p;            p += (size_t)N_NODES * 128 * 4;
    float* xB  = (float*)p;            p += (size_t)N_NODES * 128 * 4;
    int* cnt       = (int*)p;          p += (size_t)NSEG * 4;
    int* rowptr    = (int*)p;          p += (size_t)(NSEG + 1) * 4;
    int* cursor    = (int*)p;          p += (size_t)NSEG * 4;
    int* srcSorted = (int*)p;          p += (size_t)N_EDGES * 4;
    int* blockSums = (int*)p;          p += (size_t)256 * 4;
    p = (char*)align64((size_t)p);
    // swizzled weights (shorts)
    short* bz_cat = (short*)p;         p += (size_t)6 * 32768 * 2;   // 5 rel + root
    short* bz_in  = (short*)p;         p += (size_t)32768 * 2;
    short* bz_o1  = (short*)p;         p += (size_t)32768 * 2;
    short* bz_des = (short*)p;         p += (size_t)24 * 2048 * 2;
    short* bz_tw  = (short*)p;         p += (size_t)24 * 2048 * 2;

    // 0. weight prep
    for (int r = 0; r < R_REL; r++)
        build_bswz<<<8, 256, 0, stream>>>(rel_w + (size_t)r * 128 * 128, 128, 128, 8,
                                          bz_cat + (size_t)r * 32768);
    build_bswz<<<8, 256, 0, stream>>>(root_w, 128, 128, 8, bz_cat + (size_t)5 * 32768);
    build_bswz<<<8, 256, 0, stream>>>(W_in, 128, 128, 8, bz_in);
    build_bswz<<<8, 256, 0, stream>>>(W_o1, 128, 128, 8, bz_o1);
    build_bswz<<<12, 256, 0, stream>>>(W_des, 768, 32, 2, bz_des);
    build_bswz<<<12, 256, 0, stream>>>(W_tw, 768, 32, 2, bz_tw);

    // 1. CSR build (layer-invariant)
    hipMemsetAsync(cnt, 0, (size_t)NSEG * sizeof(int), stream);
    hipMemsetAsync(cursor, 0, (size_t)NSEG * sizeof(int), stream);
    count_kernel<<<(N_EDGES + 255) / 256, 256, 0, stream>>>(edge_index, edge_type, cnt);
    scan1<<<SCAN_NB, SCAN_BS, 0, stream>>>(cnt, rowptr, blockSums);
    scan2<<<1, 256, 0, stream>>>(blockSums);
    scan3<<<SCAN_NB, SCAN_BS, 0, stream>>>(rowptr, blockSums);
    fill_kernel<<<(N_EDGES + 255) / 256, 256, 0, stream>>>(
        edge_index, edge_type, rowptr, cursor, srcSorted);

    const int gm = (N_NODES + 63) / 64;    // 782 (dense GEMMs, 64-row tiles)
    const int gm32 = (N_NODES + 31) / 32;  // 1563 (fused RGCN, 32-row tiles)

    // 2. encode -> xA fp32
    encode_small<<<(N_NODES * 64 + 255) / 256, 256, 0, stream>>>(
        num_prop, cat_prop, W_np, b_np, W_cp, b_cp, xA);
    mfma_gemm<2, true><<<gm, 256, 0, stream>>>(des, 768, bz_des, b_des, xA, N_NODES, 0);
    mfma_gemm<2, true><<<gm, 256, 0, stream>>>(tweet, 768, bz_tw, b_tw, xA, N_NODES, 32);

    // 3. input linear: xA -> xB
    mfma_gemm<8, true><<<gm, 256, 0, stream>>>(xA, 128, bz_in, b_in, xB, N_NODES, 0);

    // 4. RGCN x4 (fused gather-aggregate-GEMM)
    float* cur = xB; float* nxt = xA;
    for (int lyr = 0; lyr < 4; lyr++) {
        rgcn_fused<<<gm32, 256, 0, stream>>>(cur, rowptr, srcSorted, bz_cat, rgcn_b, nxt, N_NODES);
        float* tmp = cur; cur = nxt; nxt = tmp;
    }

    // 5. output head
    mfma_gemm<8, true><<<gm, 256, 0, stream>>>(cur, 128, bz_o1, b_o1, nxt, N_NODES, 0);
    out_proj<<<(N_NODES + 255) / 256, 256, 0, stream>>>(nxt, W_o2, b_o2, out, N_NODES);
}